// Round 10
// baseline (143.322 us; speedup 1.0000x reference)
//
#include <hip/hip_runtime.h>

// TangentSpaceLoss: loss = (1/B^2) sum_ij softmax_j(E E^T)_ij * ||v_i - v_j||^2
// B=8192, G=512, D=64.
//
// R23: R22 post-mortem — WRITE_SIZE 4.06MB = 100% atomic volume => predicate
// hits ~every row (thr = min(ne)-32 ~ 25±9 vs acc ~ N(0,8): p~1%/element,
// ~1 per imHit scope). R22's skip logic never skipped: pure overhead
// (+15.5us, branches broke MFMA/shuffle interleaving). REVERTED.
// R23: base = R20 EXACT (proven 122.5us: separate k_red, no fold); ONE
// change: S epilogue goes UNCONDITIONAL — delete predicate/ballot/branches,
// always accumulate wiw=exp(s-nei), wjw=exp(s-nej) (trans pipe, branchless,
// full ILP; underflow clean at e^-87; exact reference math — the exp(-32)
// tail terms are in the reference too). Diag blocks: uniform branch +
// cndmask (ig<jg) zeroing. Predict: S 27.4 -> ~10-14us, k_mega -> ~44-50,
// total ~108-115. If flat: S fat = EFh loads/shuffles -> stage EFh next.
//   G: LDS-staged fp8 MFMA K=512 (m97): lane-linear VF8, 16x
//      global_load_lds(16B)/chunk, dbuf, 1 barrier/chunk, linear ds_read_b128.
//   S: fp16 MFMA (EFh frag-linear, B-frags hoisted), unconditional exp
//      accumulate; LDS-plane cross-wave combine (R8-verified).
// Softmax shift ne_i (= row max a.s.); diagonal w=1, wd=0 -> Z preinit 1.
// LDS: 32K dbuf + 2K norms + 4K scr = 39KB, (256,3) holds.
//
// VF8: [rt 512][c 8][lane 64][16B]; lane l = q*16+m holds A-row m,
// K-quad q (bytes 0-7 = kc0, 8-15 = kc1).
// EFh: [rt 512][kc 2][m 16][k' 32] halfs.

typedef _Float16 half8 __attribute__((ext_vector_type(8)));
typedef float    f32x4 __attribute__((ext_vector_type(4)));
typedef long     l2t   __attribute__((ext_vector_type(2)));

#define MFMA16(a, b, c) __builtin_amdgcn_mfma_f32_16x16x32_f16(a, b, c, 0, 0, 0)
#define MFMA8(a, b, c)  __builtin_amdgcn_mfma_f32_16x16x32_fp8_fp8(a, b, c, 0, 0, 0)

// Shared super-tile decode: blk0 -> (bx<=by), XCD-windowed.
__device__ __forceinline__ void st_decode(int blk0, int& bx, int& by) {
    int g = (blk0 & 7) * 260 + (blk0 >> 3);
    int SY = 0;
#pragma unroll
    for (int s = 1; s < 8; ++s) if (32 * s * s + 4 * s <= g) SY = s;
    int rr = g - (32 * SY * SY + 4 * SY);
    if (rr < 64 * SY) {                         // off-diagonal ST (full 8x8)
        int SX = rr >> 6, t = rr & 63;
        bx = (SX << 3) + (t & 7);
        by = (SY << 3) + (t >> 3);
    } else {                                    // diagonal ST (36 blocks)
        int t = rr - 64 * SY;
        int ly = 0;
#pragma unroll
        for (int s = 1; s < 8; ++s) if (s * (s + 1) / 2 <= t) ly = s;
        int lx = t - ly * (ly + 1) / 2;
        bx = (SY << 3) + lx;
        by = (SY << 3) + ly;
    }
}

// ---------------- K1: norms + fp8 V + fp16 E layouts + Z/num init -------
__global__ __launch_bounds__(256) void k_prep(
    const float* __restrict__ V, const float* __restrict__ E,
    float* __restrict__ n, float* __restrict__ ne,
    float* __restrict__ Z, float* __restrict__ num,
    unsigned char* __restrict__ VF8, _Float16* __restrict__ EFh,
    unsigned* __restrict__ cnt) {
    int rt = blockIdx.x;                       // 512 row-tiles of 16 rows
    int tid = threadIdx.x, wave = tid >> 6, lane = tid & 63;
    if (rt == 0 && tid == 0) *cnt = 0;
    int m = lane >> 2, q = lane & 3;
    int row = rt * 16 + m;
    const float* vr = V + (size_t)row * 512;
    float sn = 0.f;
#pragma unroll
    for (int it = 0; it < 2; ++it) {
        int c = wave + it * 4;                 // K-chunk of 64
        const float4* p0 = (const float4*)(vr + c * 64 + q * 8);
        const float4* p1 = (const float4*)(vr + c * 64 + 32 + q * 8);
        float4 a0 = p0[0], a1 = p0[1], b0 = p1[0], b1 = p1[1];
        int w0 = 0, w1 = 0, w2 = 0, w3 = 0;
        w0 = __builtin_amdgcn_cvt_pk_fp8_f32(a0.x, a0.y, w0, false);
        w0 = __builtin_amdgcn_cvt_pk_fp8_f32(a0.z, a0.w, w0, true);
        w1 = __builtin_amdgcn_cvt_pk_fp8_f32(a1.x, a1.y, w1, false);
        w1 = __builtin_amdgcn_cvt_pk_fp8_f32(a1.z, a1.w, w1, true);
        w2 = __builtin_amdgcn_cvt_pk_fp8_f32(b0.x, b0.y, w2, false);
        w2 = __builtin_amdgcn_cvt_pk_fp8_f32(b0.z, b0.w, w2, true);
        w3 = __builtin_amdgcn_cvt_pk_fp8_f32(b1.x, b1.y, w3, false);
        w3 = __builtin_amdgcn_cvt_pk_fp8_f32(b1.z, b1.w, w3, true);
        uint4 o;
        o.x = (unsigned)w0; o.y = (unsigned)w1;
        o.z = (unsigned)w2; o.w = (unsigned)w3;
        // LANE-LINEAR layout: frag for (m,q) -> reader-lane l = q*16+m,
        // byte offset l*16 = (q<<8) + (m<<4).
        *(uint4*)(VF8 + (((size_t)rt * 8 + c) << 10) + ((size_t)q << 8) + ((size_t)m << 4)) = o;
        sn += a0.x*a0.x + a0.y*a0.y + a0.z*a0.z + a0.w*a0.w
            + a1.x*a1.x + a1.y*a1.y + a1.z*a1.z + a1.w*a1.w
            + b0.x*b0.x + b0.y*b0.y + b0.z*b0.z + b0.w*b0.w
            + b1.x*b1.x + b1.y*b1.y + b1.z*b1.z + b1.w*b1.w;
    }
    __shared__ float sred[4][64];
    sred[wave][lane] = sn;
    __syncthreads();
    if (tid < 16) {
        float s = 0.f;
#pragma unroll
        for (int w = 0; w < 4; ++w)
#pragma unroll
            for (int qq = 0; qq < 4; ++qq) s += sred[w][tid * 4 + qq];
        int rr = rt * 16 + tid;
        n[rr] = s;
        Z[rr] = 1.0f;                          // diagonal w=1, wd=0
        num[rr] = 0.0f;
    }
    // E: threads 0..127: rl = t>>3, u = t&7, k in [u*8, u*8+8)
    if (tid < 128) {
        int rl = tid >> 3, u = tid & 7;
        int erow = rt * 16 + rl;
        const float4* er = (const float4*)(E + (size_t)erow * 64);
        float4 x0 = er[u * 2], x1 = er[u * 2 + 1];
        float xf[8] = {x0.x, x0.y, x0.z, x0.w, x1.x, x1.y, x1.z, x1.w};
        half8 h;
        float se = 0.f;
#pragma unroll
        for (int k = 0; k < 8; ++k) {
            h[k] = (_Float16)xf[k];
            se += xf[k] * xf[k];
        }
        int kc = u >> 2, qq = u & 3;
        *(half8*)(EFh + ((size_t)rt * 2 + kc) * 512 + rl * 32 + qq * 8) = h;
        se += __shfl_xor(se, 1, 64);
        se += __shfl_xor(se, 2, 64);
        se += __shfl_xor(se, 4, 64);
        if (u == 0) ne[erow] = se;
    }
}

// ---------------- K2: LDS-staged tile kernel (m97 structure) ------------
// 256 thr = 4 waves in 2x2 grid; wave tile 64x64 = 4x4 MFMA tiles.
// Per K-chunk: 16 async global_load_lds (4/wave) stage 16KB; dbuf; 1 barrier.
__global__ __launch_bounds__(256, 3) void k_mega(
    const unsigned char* __restrict__ VF8, const _Float16* __restrict__ EFh,
    const float* __restrict__ ne, const float* __restrict__ nrm,
    float* __restrict__ Z, float* __restrict__ num) {
    int bx, by;
    st_decode(blockIdx.x, bx, by);
    int i0 = bx << 7, j0 = by << 7;
    bool diag = (bx == by);

    __shared__ unsigned char ldsV[2][16384];   // [buf][slot 16][1KB]; 0-7 A, 8-15 B
    __shared__ float sNeI[128], sNeJ[128], sNI[128], sNJ[128];
    __shared__ float scr[1024];

    int tid = threadIdx.x;
    if (tid < 128) { sNeI[tid] = ne[i0 + tid]; sNI[tid] = nrm[i0 + tid]; }
    else { sNeJ[tid - 128] = ne[j0 + tid - 128]; sNJ[tid - 128] = nrm[j0 + tid - 128]; }

    int wave = tid >> 6, lane = tid & 63;
    int m = lane & 15, quad = lane >> 4;
    int wi = wave & 1, wj = wave >> 1;
    int rtA0 = i0 >> 4, rtB0 = j0 >> 4;
    size_t loH = (size_t)(m * 32 + quad * 8);   // halfs (E frags)
    size_t lo16 = (size_t)lane << 4;            // lane-linear 16B frag offset

    __syncthreads();   // norms staged (also pre-loop barrier)

    // stage slot s (0-7: A rt rtA0+s; 8-15: B rt rtB0+s-8), chunk c -> buf
#define STAGE(buf, c)                                                           \
    {                                                                           \
        _Pragma("unroll")                                                       \
        for (int k = 0; k < 4; ++k) {                                           \
            int s = (wave << 2) + k;                                            \
            int rt = (s < 8) ? (rtA0 + s) : (rtB0 + s - 8);                     \
            __builtin_amdgcn_global_load_lds(                                   \
                (const unsigned int*)(VF8 + (((size_t)rt * 8 + (c)) << 10) + lo16), \
                (unsigned int*)(&ldsV[buf][(size_t)s << 10]), 16, 0, 0);        \
        }                                                                       \
    }

    // ---- G phase: K=512, 8 chunks; async-staged LDS, dbuf, 1 barrier/chunk
    f32x4 gacc[4][4] = {};
    STAGE(0, 0);
#pragma unroll
    for (int c = 0; c < 8; ++c) {
        __syncthreads();                       // buf[c&1] staged (vmcnt0+bar)
        if (c < 7) STAGE((c + 1) & 1, c + 1);  // async into other buf (race-free)
        l2t a[4], b[4];
#pragma unroll
        for (int im = 0; im < 4; ++im)
            a[im] = *(const l2t*)(&ldsV[c & 1][(size_t)((wi << 2) + im) << 10] + lo16);
#pragma unroll
        for (int jn = 0; jn < 4; ++jn)
            b[jn] = *(const l2t*)(&ldsV[c & 1][(size_t)(8 + (wj << 2) + jn) << 10] + lo16);
#pragma unroll
        for (int jn = 0; jn < 4; ++jn)
#pragma unroll
            for (int im = 0; im < 4; ++im) {
                gacc[im][jn] = MFMA8(a[im][0], b[jn][0], gacc[im][jn]);
                gacc[im][jn] = MFMA8(a[im][1], b[jn][1], gacc[im][jn]);
            }
    }
#undef STAGE

    // ---- fused S phase + UNCONDITIONAL exp epilogue (R23) ----
    int rtA = rtA0 + wi * 4;
    int rtB = rtB0 + wj * 4;
    half8 bh[4][2];
#pragma unroll
    for (int jn = 0; jn < 4; ++jn) {
        size_t bb = (size_t)(rtB + jn) * 2 * 512 + loH;
        bh[jn][0] = *(const half8*)(EFh + bb);
        bh[jn][1] = *(const half8*)(EFh + bb + 512);
    }
    float zj[4] = {}, nj_[4] = {};
#pragma unroll
    for (int im = 0; im < 4; ++im) {
        size_t ab = (size_t)(rtA + im) * 2 * 512 + loH;
        half8 ah0 = *(const half8*)(EFh + ab);
        half8 ah1 = *(const half8*)(EFh + ab + 512);
        f32x4 zi4 = {0.f, 0.f, 0.f, 0.f};
        f32x4 ni4 = {0.f, 0.f, 0.f, 0.f};
#pragma unroll
        for (int jn = 0; jn < 4; ++jn) {
            f32x4 acc = {0.f, 0.f, 0.f, 0.f};
            acc = MFMA16(ah0, bh[jn][0], acc);
            acc = MFMA16(ah1, bh[jn][1], acc);
            int jl = (wj << 6) + jn * 16 + m;
            int jg = j0 + jl;
            float nej = sNeJ[jl], nnj = sNJ[jl];
            f32x4 g4 = gacc[im][jn];
#pragma unroll
            for (int r = 0; r < 4; ++r) {
                int il = (wi << 6) + im * 16 + quad * 4 + r;
                float nei = sNeI[il], nni = sNI[il];
                float s = acc[r];
                float wiw = __expf(s - nei);   // exact softmax term (shift=nei)
                float wjw = __expf(s - nej);
                if (diag) {                    // uniform branch; cndmask inner
                    bool keep = (i0 + il) < jg;
                    wiw = keep ? wiw : 0.f;
                    wjw = keep ? wjw : 0.f;
                }
                float wd = nni + nnj - 2.f * g4[r];
                zi4[r] += wiw;  ni4[r] += wiw * wd;
                zj[jn] += wjw;  nj_[jn] += wjw * wd;
            }
        }
        // i-side: reduce over 16 m-lanes, write wj-plane
#pragma unroll
        for (int msk = 1; msk < 16; msk <<= 1) {
#pragma unroll
            for (int r = 0; r < 4; ++r) {
                zi4[r] += __shfl_xor(zi4[r], msk, 64);
                ni4[r] += __shfl_xor(ni4[r], msk, 64);
            }
        }
        if (m == 0) {
            int row0 = (wi << 6) + im * 16 + quad * 4;
            *(f32x4*)(scr + (wj << 7) + row0)       = zi4;
            *(f32x4*)(scr + 256 + (wj << 7) + row0) = ni4;
        }
    }
    // j-side: reduce over quads, write wi-plane
#pragma unroll
    for (int msk = 16; msk < 64; msk <<= 1) {
#pragma unroll
        for (int jn = 0; jn < 4; ++jn) {
            zj[jn]  += __shfl_xor(zj[jn],  msk, 64);
            nj_[jn] += __shfl_xor(nj_[jn], msk, 64);
        }
    }
    if (quad == 0) {
#pragma unroll
        for (int jn = 0; jn < 4; ++jn) {
            int jl = (wj << 6) + jn * 16 + m;
            scr[512 + (wi << 7) + jl] = zj[jn];
            scr[768 + (wi << 7) + jl] = nj_[jn];
        }
    }
    __syncthreads();
    // fold planes -> direct device atomics
    if (tid < 128) {
        float az = scr[tid]       + scr[128 + tid];
        float an = scr[256 + tid] + scr[384 + tid];
        atomicAdd(Z + i0 + tid,   az);
        atomicAdd(num + i0 + tid, an);
    } else {
        int cidx = tid - 128;
        float az = scr[512 + cidx] + scr[640 + cidx];
        float an = scr[768 + cidx] + scr[896 + cidx];
        atomicAdd(Z + j0 + cidx,   az);
        atomicAdd(num + j0 + cidx, an);
    }
}

// ------- K3: trivial 8192-row reduce + last-block final fold ------------
__global__ __launch_bounds__(256) void k_red(
    const float* __restrict__ Z, const float* __restrict__ num,
    double* __restrict__ part, unsigned* __restrict__ cnt,
    float* __restrict__ out) {
    int r = (blockIdx.x << 8) + threadIdx.x;   // 32 blocks x 256 threads
    __shared__ double sd[256];
    sd[threadIdx.x] = (double)num[r] / (double)Z[r];
    __syncthreads();
    for (int st = 128; st > 0; st >>= 1) {
        if (threadIdx.x < st) sd[threadIdx.x] += sd[threadIdx.x + st];
        __syncthreads();
    }
    if (threadIdx.x == 0) {
        part[blockIdx.x] = sd[0];
        __threadfence();
        unsigned old = atomicAdd(cnt, 1u);
        if (old == 31u) {                // last block folds
            __threadfence();
            double a = 0.0;
            for (int k = 0; k < 32; ++k) a += part[k];
            out[0] = (float)(a / 67108864.0);   // / B^2
        }
    }
}

// ---------------- host launcher -----------------------------------------
extern "C" void kernel_launch(void* const* d_in, const int* in_sizes, int n_in,
                              void* d_out, int out_size, void* d_ws, size_t ws_size,
                              hipStream_t stream) {
    const float* V = (const float*)d_in[0];   // [8192, 512] f32
    const float* E = (const float*)d_in[1];   // [8192, 64]  f32
    float* out = (float*)d_out;
    char* ws = (char*)d_ws;

    float*         n_   = (float*)(ws + 0);            // 32 KB
    float*         ne   = (float*)(ws + 32768);        // 32 KB
    float*         Z    = (float*)(ws + 65536);        // 32 KB (init 1 in k_prep)
    float*         num  = (float*)(ws + 98304);        // 32 KB (init 0 in k_prep)
    unsigned char* VF8  = (unsigned char*)(ws + 131072);// 4 MB fp8 V frags
    _Float16*      EFh  = (_Float16*)(ws + 4325376);   // 1 MB
    double*        part = (double*)(ws + 5373952);     // 256 B
    unsigned*      cnt  = (unsigned*)(ws + 5374208);   // 4 B

    k_prep<<<512, 256, 0, stream>>>(V, E, n_, ne, Z, num, VF8, EFh, cnt);
    k_mega<<<2080, 256, 0, stream>>>(VF8, EFh, ne, n_, Z, num);
    k_red <<<32, 256, 0, stream>>>(Z, num, part, cnt, out);
}

// Round 11
// 132.647 us; speedup vs baseline: 1.0805x; 1.0805x over previous
//
#include <hip/hip_runtime.h>

// TangentSpaceLoss: loss = (1/B^2) sum_ij softmax_j(E E^T)_ij * ||v_i - v_j||^2
// B=8192, G=512, D=64.
//
// R24: R23 post-mortem — unconditional epilogue SPILLED (FETCH 83.6MB /
// WRITE 124.8MB vs 5MB working set = ~240B/thread scratch): with no branches
// and full unroll, the scheduler hoisted all 16 tiles' MFMA16s and kept ~16
// f32x4 accs + exp temps live -> blew the 168-reg cap (64 AGPR gacc + 84V).
// R20's branches were accidental scheduling fences. R24 keeps the
// unconditional math but fences explicitly:
//  (1) sched_barrier(0) after EACH (im,jn) tile -> 1 live acc, no spill.
//  (2) factored softmax: wiw = e^s * ci, ci=exp(-ne_i) precomputed in LDS
//      (sCi/sCj replace sNeI/sNeJ); inner = 1 exp + 2 mul (was 2 exp+2 sub).
//      Range-safe: s<=~40 -> e^s<=2e17; ci FTZ-zero only for rows with true
//      contribution <=1e-22 (negligible vs 1e-10 tolerance).
// Else R20-exact (separate k_red, proven path).
// Predict: WRITE ->4.1MB, FETCH ->13.3MB, VGPR ~90 no scratch, k_mega
// ->40-48us, total ~105-112us. If WRITE still >>5MB -> revert to R20 next.
//   G: LDS-staged fp8 MFMA K=512 (m97): lane-linear VF8, 16x
//      global_load_lds(16B)/chunk, dbuf, 1 barrier/chunk, linear ds_read_b128.
//   S: fp16 MFMA (EFh frag-linear, B-frags hoisted), unconditional factored
//      exp accumulate, per-tile sched_barrier; LDS-plane cross-wave combine.
// Softmax shift ne_i; diagonal w=1, wd=0 -> Z preinit 1.
// LDS: 32K dbuf + 2K norms + 4K scr = 39KB, (256,3) holds.
//
// VF8: [rt 512][c 8][lane 64][16B]; lane l = q*16+m holds A-row m,
// K-quad q (bytes 0-7 = kc0, 8-15 = kc1).
// EFh: [rt 512][kc 2][m 16][k' 32] halfs.

typedef _Float16 half8 __attribute__((ext_vector_type(8)));
typedef float    f32x4 __attribute__((ext_vector_type(4)));
typedef long     l2t   __attribute__((ext_vector_type(2)));

#define MFMA16(a, b, c) __builtin_amdgcn_mfma_f32_16x16x32_f16(a, b, c, 0, 0, 0)
#define MFMA8(a, b, c)  __builtin_amdgcn_mfma_f32_16x16x32_fp8_fp8(a, b, c, 0, 0, 0)

// Shared super-tile decode: blk0 -> (bx<=by), XCD-windowed.
__device__ __forceinline__ void st_decode(int blk0, int& bx, int& by) {
    int g = (blk0 & 7) * 260 + (blk0 >> 3);
    int SY = 0;
#pragma unroll
    for (int s = 1; s < 8; ++s) if (32 * s * s + 4 * s <= g) SY = s;
    int rr = g - (32 * SY * SY + 4 * SY);
    if (rr < 64 * SY) {                         // off-diagonal ST (full 8x8)
        int SX = rr >> 6, t = rr & 63;
        bx = (SX << 3) + (t & 7);
        by = (SY << 3) + (t >> 3);
    } else {                                    // diagonal ST (36 blocks)
        int t = rr - 64 * SY;
        int ly = 0;
#pragma unroll
        for (int s = 1; s < 8; ++s) if (s * (s + 1) / 2 <= t) ly = s;
        int lx = t - ly * (ly + 1) / 2;
        bx = (SY << 3) + lx;
        by = (SY << 3) + ly;
    }
}

// ---------------- K1: norms + fp8 V + fp16 E layouts + Z/num init -------
__global__ __launch_bounds__(256) void k_prep(
    const float* __restrict__ V, const float* __restrict__ E,
    float* __restrict__ n, float* __restrict__ ne,
    float* __restrict__ Z, float* __restrict__ num,
    unsigned char* __restrict__ VF8, _Float16* __restrict__ EFh,
    unsigned* __restrict__ cnt) {
    int rt = blockIdx.x;                       // 512 row-tiles of 16 rows
    int tid = threadIdx.x, wave = tid >> 6, lane = tid & 63;
    if (rt == 0 && tid == 0) *cnt = 0;
    int m = lane >> 2, q = lane & 3;
    int row = rt * 16 + m;
    const float* vr = V + (size_t)row * 512;
    float sn = 0.f;
#pragma unroll
    for (int it = 0; it < 2; ++it) {
        int c = wave + it * 4;                 // K-chunk of 64
        const float4* p0 = (const float4*)(vr + c * 64 + q * 8);
        const float4* p1 = (const float4*)(vr + c * 64 + 32 + q * 8);
        float4 a0 = p0[0], a1 = p0[1], b0 = p1[0], b1 = p1[1];
        int w0 = 0, w1 = 0, w2 = 0, w3 = 0;
        w0 = __builtin_amdgcn_cvt_pk_fp8_f32(a0.x, a0.y, w0, false);
        w0 = __builtin_amdgcn_cvt_pk_fp8_f32(a0.z, a0.w, w0, true);
        w1 = __builtin_amdgcn_cvt_pk_fp8_f32(a1.x, a1.y, w1, false);
        w1 = __builtin_amdgcn_cvt_pk_fp8_f32(a1.z, a1.w, w1, true);
        w2 = __builtin_amdgcn_cvt_pk_fp8_f32(b0.x, b0.y, w2, false);
        w2 = __builtin_amdgcn_cvt_pk_fp8_f32(b0.z, b0.w, w2, true);
        w3 = __builtin_amdgcn_cvt_pk_fp8_f32(b1.x, b1.y, w3, false);
        w3 = __builtin_amdgcn_cvt_pk_fp8_f32(b1.z, b1.w, w3, true);
        uint4 o;
        o.x = (unsigned)w0; o.y = (unsigned)w1;
        o.z = (unsigned)w2; o.w = (unsigned)w3;
        // LANE-LINEAR layout: frag for (m,q) -> reader-lane l = q*16+m,
        // byte offset l*16 = (q<<8) + (m<<4).
        *(uint4*)(VF8 + (((size_t)rt * 8 + c) << 10) + ((size_t)q << 8) + ((size_t)m << 4)) = o;
        sn += a0.x*a0.x + a0.y*a0.y + a0.z*a0.z + a0.w*a0.w
            + a1.x*a1.x + a1.y*a1.y + a1.z*a1.z + a1.w*a1.w
            + b0.x*b0.x + b0.y*b0.y + b0.z*b0.z + b0.w*b0.w
            + b1.x*b1.x + b1.y*b1.y + b1.z*b1.z + b1.w*b1.w;
    }
    __shared__ float sred[4][64];
    sred[wave][lane] = sn;
    __syncthreads();
    if (tid < 16) {
        float s = 0.f;
#pragma unroll
        for (int w = 0; w < 4; ++w)
#pragma unroll
            for (int qq = 0; qq < 4; ++qq) s += sred[w][tid * 4 + qq];
        int rr = rt * 16 + tid;
        n[rr] = s;
        Z[rr] = 1.0f;                          // diagonal w=1, wd=0
        num[rr] = 0.0f;
    }
    // E: threads 0..127: rl = t>>3, u = t&7, k in [u*8, u*8+8)
    if (tid < 128) {
        int rl = tid >> 3, u = tid & 7;
        int erow = rt * 16 + rl;
        const float4* er = (const float4*)(E + (size_t)erow * 64);
        float4 x0 = er[u * 2], x1 = er[u * 2 + 1];
        float xf[8] = {x0.x, x0.y, x0.z, x0.w, x1.x, x1.y, x1.z, x1.w};
        half8 h;
        float se = 0.f;
#pragma unroll
        for (int k = 0; k < 8; ++k) {
            h[k] = (_Float16)xf[k];
            se += xf[k] * xf[k];
        }
        int kc = u >> 2, qq = u & 3;
        *(half8*)(EFh + ((size_t)rt * 2 + kc) * 512 + rl * 32 + qq * 8) = h;
        se += __shfl_xor(se, 1, 64);
        se += __shfl_xor(se, 2, 64);
        se += __shfl_xor(se, 4, 64);
        if (u == 0) ne[erow] = se;
    }
}

// ---------------- K2: LDS-staged tile kernel (m97 structure) ------------
// 256 thr = 4 waves in 2x2 grid; wave tile 64x64 = 4x4 MFMA tiles.
// Per K-chunk: 16 async global_load_lds (4/wave) stage 16KB; dbuf; 1 barrier.
__global__ __launch_bounds__(256, 3) void k_mega(
    const unsigned char* __restrict__ VF8, const _Float16* __restrict__ EFh,
    const float* __restrict__ ne, const float* __restrict__ nrm,
    float* __restrict__ Z, float* __restrict__ num) {
    int bx, by;
    st_decode(blockIdx.x, bx, by);
    int i0 = bx << 7, j0 = by << 7;
    bool diag = (bx == by);

    __shared__ unsigned char ldsV[2][16384];   // [buf][slot 16][1KB]; 0-7 A, 8-15 B
    __shared__ float sCi[128], sCj[128], sNI[128], sNJ[128];
    __shared__ float scr[1024];

    int tid = threadIdx.x;
    // factored softmax constants: ci = exp(-ne_i), cj = exp(-ne_j)
    if (tid < 128) { sCi[tid] = __expf(-ne[i0 + tid]); sNI[tid] = nrm[i0 + tid]; }
    else { sCj[tid - 128] = __expf(-ne[j0 + tid - 128]); sNJ[tid - 128] = nrm[j0 + tid - 128]; }

    int wave = tid >> 6, lane = tid & 63;
    int m = lane & 15, quad = lane >> 4;
    int wi = wave & 1, wj = wave >> 1;
    int rtA0 = i0 >> 4, rtB0 = j0 >> 4;
    size_t loH = (size_t)(m * 32 + quad * 8);   // halfs (E frags)
    size_t lo16 = (size_t)lane << 4;            // lane-linear 16B frag offset

    __syncthreads();   // norms staged (also pre-loop barrier)

    // stage slot s (0-7: A rt rtA0+s; 8-15: B rt rtB0+s-8), chunk c -> buf
#define STAGE(buf, c)                                                           \
    {                                                                           \
        _Pragma("unroll")                                                       \
        for (int k = 0; k < 4; ++k) {                                           \
            int s = (wave << 2) + k;                                            \
            int rt = (s < 8) ? (rtA0 + s) : (rtB0 + s - 8);                     \
            __builtin_amdgcn_global_load_lds(                                   \
                (const unsigned int*)(VF8 + (((size_t)rt * 8 + (c)) << 10) + lo16), \
                (unsigned int*)(&ldsV[buf][(size_t)s << 10]), 16, 0, 0);        \
        }                                                                       \
    }

    // ---- G phase: K=512, 8 chunks; async-staged LDS, dbuf, 1 barrier/chunk
    f32x4 gacc[4][4] = {};
    STAGE(0, 0);
#pragma unroll
    for (int c = 0; c < 8; ++c) {
        __syncthreads();                       // buf[c&1] staged (vmcnt0+bar)
        if (c < 7) STAGE((c + 1) & 1, c + 1);  // async into other buf (race-free)
        l2t a[4], b[4];
#pragma unroll
        for (int im = 0; im < 4; ++im)
            a[im] = *(const l2t*)(&ldsV[c & 1][(size_t)((wi << 2) + im) << 10] + lo16);
#pragma unroll
        for (int jn = 0; jn < 4; ++jn)
            b[jn] = *(const l2t*)(&ldsV[c & 1][(size_t)(8 + (wj << 2) + jn) << 10] + lo16);
#pragma unroll
        for (int jn = 0; jn < 4; ++jn)
#pragma unroll
            for (int im = 0; im < 4; ++im) {
                gacc[im][jn] = MFMA8(a[im][0], b[jn][0], gacc[im][jn]);
                gacc[im][jn] = MFMA8(a[im][1], b[jn][1], gacc[im][jn]);
            }
    }
#undef STAGE

    // ---- fused S phase + unconditional factored-exp epilogue (R24) ----
    int rtA = rtA0 + wi * 4;
    int rtB = rtB0 + wj * 4;
    half8 bh[4][2];
#pragma unroll
    for (int jn = 0; jn < 4; ++jn) {
        size_t bb = (size_t)(rtB + jn) * 2 * 512 + loH;
        bh[jn][0] = *(const half8*)(EFh + bb);
        bh[jn][1] = *(const half8*)(EFh + bb + 512);
    }
    float zj[4] = {}, nj_[4] = {};
#pragma unroll
    for (int im = 0; im < 4; ++im) {
        size_t ab = (size_t)(rtA + im) * 2 * 512 + loH;
        half8 ah0 = *(const half8*)(EFh + ab);
        half8 ah1 = *(const half8*)(EFh + ab + 512);
        f32x4 zi4 = {0.f, 0.f, 0.f, 0.f};
        f32x4 ni4 = {0.f, 0.f, 0.f, 0.f};
#pragma unroll
        for (int jn = 0; jn < 4; ++jn) {
            f32x4 acc = {0.f, 0.f, 0.f, 0.f};
            acc = MFMA16(ah0, bh[jn][0], acc);
            acc = MFMA16(ah1, bh[jn][1], acc);
            int jl = (wj << 6) + jn * 16 + m;
            int jg = j0 + jl;
            float cj = sCj[jl], nnj = sNJ[jl];
            f32x4 g4 = gacc[im][jn];
#pragma unroll
            for (int r = 0; r < 4; ++r) {
                int il = (wi << 6) + im * 16 + quad * 4 + r;
                float ci = sCi[il], nni = sNI[il];
                float es = __expf(acc[r]);     // one exp; wiw = es*ci, wjw = es*cj
                float wiw = es * ci;
                float wjw = es * cj;
                if (diag) {                    // uniform branch; cndmask inner
                    bool keep = (i0 + il) < jg;
                    wiw = keep ? wiw : 0.f;
                    wjw = keep ? wjw : 0.f;
                }
                float wd = nni + nnj - 2.f * g4[r];
                zi4[r] += wiw;  ni4[r] += wiw * wd;
                zj[jn] += wjw;  nj_[jn] += wjw * wd;
            }
            // fence: cap scheduler window to one tile (R23 spill killer)
            __builtin_amdgcn_sched_barrier(0);
        }
        // i-side: reduce over 16 m-lanes, write wj-plane
#pragma unroll
        for (int msk = 1; msk < 16; msk <<= 1) {
#pragma unroll
            for (int r = 0; r < 4; ++r) {
                zi4[r] += __shfl_xor(zi4[r], msk, 64);
                ni4[r] += __shfl_xor(ni4[r], msk, 64);
            }
        }
        if (m == 0) {
            int row0 = (wi << 6) + im * 16 + quad * 4;
            *(f32x4*)(scr + (wj << 7) + row0)       = zi4;
            *(f32x4*)(scr + 256 + (wj << 7) + row0) = ni4;
        }
    }
    // j-side: reduce over quads, write wi-plane
#pragma unroll
    for (int msk = 16; msk < 64; msk <<= 1) {
#pragma unroll
        for (int jn = 0; jn < 4; ++jn) {
            zj[jn]  += __shfl_xor(zj[jn],  msk, 64);
            nj_[jn] += __shfl_xor(nj_[jn], msk, 64);
        }
    }
    if (quad == 0) {
#pragma unroll
        for (int jn = 0; jn < 4; ++jn) {
            int jl = (wj << 6) + jn * 16 + m;
            scr[512 + (wi << 7) + jl] = zj[jn];
            scr[768 + (wi << 7) + jl] = nj_[jn];
        }
    }
    __syncthreads();
    // fold planes -> direct device atomics
    if (tid < 128) {
        float az = scr[tid]       + scr[128 + tid];
        float an = scr[256 + tid] + scr[384 + tid];
        atomicAdd(Z + i0 + tid,   az);
        atomicAdd(num + i0 + tid, an);
    } else {
        int cidx = tid - 128;
        float az = scr[512 + cidx] + scr[640 + cidx];
        float an = scr[768 + cidx] + scr[896 + cidx];
        atomicAdd(Z + j0 + cidx,   az);
        atomicAdd(num + j0 + cidx, an);
    }
}

// ------- K3: trivial 8192-row reduce + last-block final fold ------------
__global__ __launch_bounds__(256) void k_red(
    const float* __restrict__ Z, const float* __restrict__ num,
    double* __restrict__ part, unsigned* __restrict__ cnt,
    float* __restrict__ out) {
    int r = (blockIdx.x << 8) + threadIdx.x;   // 32 blocks x 256 threads
    __shared__ double sd[256];
    sd[threadIdx.x] = (double)num[r] / (double)Z[r];
    __syncthreads();
    for (int st = 128; st > 0; st >>= 1) {
        if (threadIdx.x < st) sd[threadIdx.x] += sd[threadIdx.x + st];
        __syncthreads();
    }
    if (threadIdx.x == 0) {
        part[blockIdx.x] = sd[0];
        __threadfence();
        unsigned old = atomicAdd(cnt, 1u);
        if (old == 31u) {                // last block folds
            __threadfence();
            double a = 0.0;
            for (int k = 0; k < 32; ++k) a += part[k];
            out[0] = (float)(a / 67108864.0);   // / B^2
        }
    }
}

// ---------------- host launcher -----------------------------------------
extern "C" void kernel_launch(void* const* d_in, const int* in_sizes, int n_in,
                              void* d_out, int out_size, void* d_ws, size_t ws_size,
                              hipStream_t stream) {
    const float* V = (const float*)d_in[0];   // [8192, 512] f32
    const float* E = (const float*)d_in[1];   // [8192, 64]  f32
    float* out = (float*)d_out;
    char* ws = (char*)d_ws;

    float*         n_   = (float*)(ws + 0);            // 32 KB
    float*         ne   = (float*)(ws + 32768);        // 32 KB
    float*         Z    = (float*)(ws + 65536);        // 32 KB (init 1 in k_prep)
    float*         num  = (float*)(ws + 98304);        // 32 KB (init 0 in k_prep)
    unsigned char* VF8  = (unsigned char*)(ws + 131072);// 4 MB fp8 V frags
    _Float16*      EFh  = (_Float16*)(ws + 4325376);   // 1 MB
    double*        part = (double*)(ws + 5373952);     // 256 B
    unsigned*      cnt  = (unsigned*)(ws + 5374208);   // 4 B

    k_prep<<<512, 256, 0, stream>>>(V, E, n_, ne, Z, num, VF8, EFh, cnt);
    k_mega<<<2080, 256, 0, stream>>>(VF8, EFh, ne, n_, Z, num);
    k_red <<<32, 256, 0, stream>>>(Z, num, part, cnt, out);
}

// Round 12
// 119.048 us; speedup vs baseline: 1.2039x; 1.1142x over previous
//
#include <hip/hip_runtime.h>

// TangentSpaceLoss: loss = (1/B^2) sum_ij softmax_j(E E^T)_ij * ||v_i - v_j||^2
// B=8192, G=512, D=64.
//
// R25: R24 still spilled (WRITE 77MB): at 148/168 regs ANY unconditional
// epilogue restructure tips the allocator. Record: R20's branchy S is the
// only no-spill codegen (R21 neutral, R22 +15us, R23/R24 spill). So R25
// keeps R20's control structure EXACTLY and shrinks work inside it:
//  (1) predicate inputs -> registers: bj[jn]=sNeJ[jl]-32 (4 regs/wave);
//      per-im ONE ds_read_b128 -> ai4=nei4-32 (rows quad*4..+3 contiguous);
//      predicate = acc > fminf(ai4[r], bj). Rare branch body unchanged
//      (reads LDS). ~96 scalar ds_reads -> ~12, shorter ballot chains.
//  (2) shuffle-reduce cut: i-side 4 -> 2 stages, lanes (m&3)==0 write 4
//      partials/row (same ds_write instr count, more active lanes); j-side
//      2 -> 1 stage, 2 partials/col. Fold sums 8/4 partials. Saves 72 shfl
//      + 72 adds/wave, halves chain latency. scr 4->12KB, LDS 47KB (3/CU ok).
// G phase, k_prep, k_red: R20-exact.
// Predict: WRITE 4.06MB (spill check!), k_mega ->48-53, total ~113-118.
// If WRITE >> 5MB or k_mega >= 57: revert to R20-exact next round.
//   G: LDS-staged fp8 MFMA K=512 (m97): lane-linear VF8, 16x
//      global_load_lds(16B)/chunk, dbuf, 1 barrier/chunk, linear ds_read_b128.
//   S: fp16 MFMA (EFh frag-linear, B-frags hoisted), ballot-skip epilogue
//      (R20 structure), reg-hoisted predicates, 2-stage partial reduce.
// Selection: s > min(ne_i,ne_j)-32 (safe superset). Softmax shift ne_i;
// diagonal w=1, wd=0 -> Z preinit 1.
//
// VF8: [rt 512][c 8][lane 64][16B]; lane l = q*16+m holds A-row m,
// K-quad q (bytes 0-7 = kc0, 8-15 = kc1).
// EFh: [rt 512][kc 2][m 16][k' 32] halfs.

#define SEL_T 32.0f

typedef _Float16 half8 __attribute__((ext_vector_type(8)));
typedef float    f32x4 __attribute__((ext_vector_type(4)));
typedef long     l2t   __attribute__((ext_vector_type(2)));

#define MFMA16(a, b, c) __builtin_amdgcn_mfma_f32_16x16x32_f16(a, b, c, 0, 0, 0)
#define MFMA8(a, b, c)  __builtin_amdgcn_mfma_f32_16x16x32_fp8_fp8(a, b, c, 0, 0, 0)

// Shared super-tile decode: blk0 -> (bx<=by), XCD-windowed.
__device__ __forceinline__ void st_decode(int blk0, int& bx, int& by) {
    int g = (blk0 & 7) * 260 + (blk0 >> 3);
    int SY = 0;
#pragma unroll
    for (int s = 1; s < 8; ++s) if (32 * s * s + 4 * s <= g) SY = s;
    int rr = g - (32 * SY * SY + 4 * SY);
    if (rr < 64 * SY) {                         // off-diagonal ST (full 8x8)
        int SX = rr >> 6, t = rr & 63;
        bx = (SX << 3) + (t & 7);
        by = (SY << 3) + (t >> 3);
    } else {                                    // diagonal ST (36 blocks)
        int t = rr - 64 * SY;
        int ly = 0;
#pragma unroll
        for (int s = 1; s < 8; ++s) if (s * (s + 1) / 2 <= t) ly = s;
        int lx = t - ly * (ly + 1) / 2;
        bx = (SY << 3) + lx;
        by = (SY << 3) + ly;
    }
}

// ---------------- K1: norms + fp8 V + fp16 E layouts + Z/num init -------
__global__ __launch_bounds__(256) void k_prep(
    const float* __restrict__ V, const float* __restrict__ E,
    float* __restrict__ n, float* __restrict__ ne,
    float* __restrict__ Z, float* __restrict__ num,
    unsigned char* __restrict__ VF8, _Float16* __restrict__ EFh,
    unsigned* __restrict__ cnt) {
    int rt = blockIdx.x;                       // 512 row-tiles of 16 rows
    int tid = threadIdx.x, wave = tid >> 6, lane = tid & 63;
    if (rt == 0 && tid == 0) *cnt = 0;
    int m = lane >> 2, q = lane & 3;
    int row = rt * 16 + m;
    const float* vr = V + (size_t)row * 512;
    float sn = 0.f;
#pragma unroll
    for (int it = 0; it < 2; ++it) {
        int c = wave + it * 4;                 // K-chunk of 64
        const float4* p0 = (const float4*)(vr + c * 64 + q * 8);
        const float4* p1 = (const float4*)(vr + c * 64 + 32 + q * 8);
        float4 a0 = p0[0], a1 = p0[1], b0 = p1[0], b1 = p1[1];
        int w0 = 0, w1 = 0, w2 = 0, w3 = 0;
        w0 = __builtin_amdgcn_cvt_pk_fp8_f32(a0.x, a0.y, w0, false);
        w0 = __builtin_amdgcn_cvt_pk_fp8_f32(a0.z, a0.w, w0, true);
        w1 = __builtin_amdgcn_cvt_pk_fp8_f32(a1.x, a1.y, w1, false);
        w1 = __builtin_amdgcn_cvt_pk_fp8_f32(a1.z, a1.w, w1, true);
        w2 = __builtin_amdgcn_cvt_pk_fp8_f32(b0.x, b0.y, w2, false);
        w2 = __builtin_amdgcn_cvt_pk_fp8_f32(b0.z, b0.w, w2, true);
        w3 = __builtin_amdgcn_cvt_pk_fp8_f32(b1.x, b1.y, w3, false);
        w3 = __builtin_amdgcn_cvt_pk_fp8_f32(b1.z, b1.w, w3, true);
        uint4 o;
        o.x = (unsigned)w0; o.y = (unsigned)w1;
        o.z = (unsigned)w2; o.w = (unsigned)w3;
        // LANE-LINEAR layout: frag for (m,q) -> reader-lane l = q*16+m,
        // byte offset l*16 = (q<<8) + (m<<4).
        *(uint4*)(VF8 + (((size_t)rt * 8 + c) << 10) + ((size_t)q << 8) + ((size_t)m << 4)) = o;
        sn += a0.x*a0.x + a0.y*a0.y + a0.z*a0.z + a0.w*a0.w
            + a1.x*a1.x + a1.y*a1.y + a1.z*a1.z + a1.w*a1.w
            + b0.x*b0.x + b0.y*b0.y + b0.z*b0.z + b0.w*b0.w
            + b1.x*b1.x + b1.y*b1.y + b1.z*b1.z + b1.w*b1.w;
    }
    __shared__ float sred[4][64];
    sred[wave][lane] = sn;
    __syncthreads();
    if (tid < 16) {
        float s = 0.f;
#pragma unroll
        for (int w = 0; w < 4; ++w)
#pragma unroll
            for (int qq = 0; qq < 4; ++qq) s += sred[w][tid * 4 + qq];
        int rr = rt * 16 + tid;
        n[rr] = s;
        Z[rr] = 1.0f;                          // diagonal w=1, wd=0
        num[rr] = 0.0f;
    }
    // E: threads 0..127: rl = t>>3, u = t&7, k in [u*8, u*8+8)
    if (tid < 128) {
        int rl = tid >> 3, u = tid & 7;
        int erow = rt * 16 + rl;
        const float4* er = (const float4*)(E + (size_t)erow * 64);
        float4 x0 = er[u * 2], x1 = er[u * 2 + 1];
        float xf[8] = {x0.x, x0.y, x0.z, x0.w, x1.x, x1.y, x1.z, x1.w};
        half8 h;
        float se = 0.f;
#pragma unroll
        for (int k = 0; k < 8; ++k) {
            h[k] = (_Float16)xf[k];
            se += xf[k] * xf[k];
        }
        int kc = u >> 2, qq = u & 3;
        *(half8*)(EFh + ((size_t)rt * 2 + kc) * 512 + rl * 32 + qq * 8) = h;
        se += __shfl_xor(se, 1, 64);
        se += __shfl_xor(se, 2, 64);
        se += __shfl_xor(se, 4, 64);
        if (u == 0) ne[erow] = se;
    }
}

// ---------------- K2: LDS-staged tile kernel (m97 structure) ------------
// 256 thr = 4 waves in 2x2 grid; wave tile 64x64 = 4x4 MFMA tiles.
// Per K-chunk: 16 async global_load_lds (4/wave) stage 16KB; dbuf; 1 barrier.
__global__ __launch_bounds__(256, 3) void k_mega(
    const unsigned char* __restrict__ VF8, const _Float16* __restrict__ EFh,
    const float* __restrict__ ne, const float* __restrict__ nrm,
    float* __restrict__ Z, float* __restrict__ num) {
    int bx, by;
    st_decode(blockIdx.x, bx, by);
    int i0 = bx << 7, j0 = by << 7;
    bool diag = (bx == by);

    __shared__ unsigned char ldsV[2][16384];   // [buf][slot 16][1KB]; 0-7 A, 8-15 B
    __shared__ float sNeI[128], sNeJ[128], sNI[128], sNJ[128];
    __shared__ float scr[3072];                // widened partial planes (12KB)

    int tid = threadIdx.x;
    if (tid < 128) { sNeI[tid] = ne[i0 + tid]; sNI[tid] = nrm[i0 + tid]; }
    else { sNeJ[tid - 128] = ne[j0 + tid - 128]; sNJ[tid - 128] = nrm[j0 + tid - 128]; }

    int wave = tid >> 6, lane = tid & 63;
    int m = lane & 15, quad = lane >> 4;
    int wi = wave & 1, wj = wave >> 1;
    int rtA0 = i0 >> 4, rtB0 = j0 >> 4;
    size_t loH = (size_t)(m * 32 + quad * 8);   // halfs (E frags)
    size_t lo16 = (size_t)lane << 4;            // lane-linear 16B frag offset

    __syncthreads();   // norms staged (also pre-loop barrier)

    // stage slot s (0-7: A rt rtA0+s; 8-15: B rt rtB0+s-8), chunk c -> buf
#define STAGE(buf, c)                                                           \
    {                                                                           \
        _Pragma("unroll")                                                       \
        for (int k = 0; k < 4; ++k) {                                           \
            int s = (wave << 2) + k;                                            \
            int rt = (s < 8) ? (rtA0 + s) : (rtB0 + s - 8);                     \
            __builtin_amdgcn_global_load_lds(                                   \
                (const unsigned int*)(VF8 + (((size_t)rt * 8 + (c)) << 10) + lo16), \
                (unsigned int*)(&ldsV[buf][(size_t)s << 10]), 16, 0, 0);        \
        }                                                                       \
    }

    // ---- G phase: K=512, 8 chunks; async-staged LDS, dbuf, 1 barrier/chunk
    f32x4 gacc[4][4] = {};
    STAGE(0, 0);
#pragma unroll
    for (int c = 0; c < 8; ++c) {
        __syncthreads();                       // buf[c&1] staged (vmcnt0+bar)
        if (c < 7) STAGE((c + 1) & 1, c + 1);  // async into other buf (race-free)
        l2t a[4], b[4];
#pragma unroll
        for (int im = 0; im < 4; ++im)
            a[im] = *(const l2t*)(&ldsV[c & 1][(size_t)((wi << 2) + im) << 10] + lo16);
#pragma unroll
        for (int jn = 0; jn < 4; ++jn)
            b[jn] = *(const l2t*)(&ldsV[c & 1][(size_t)(8 + (wj << 2) + jn) << 10] + lo16);
#pragma unroll
        for (int jn = 0; jn < 4; ++jn)
#pragma unroll
            for (int im = 0; im < 4; ++im) {
                gacc[im][jn] = MFMA8(a[im][0], b[jn][0], gacc[im][jn]);
                gacc[im][jn] = MFMA8(a[im][1], b[jn][1], gacc[im][jn]);
            }
    }
#undef STAGE

    // ---- fused S phase + epilogue (R20 structure, reg-hoisted predicates)
    int rtA = rtA0 + wi * 4;
    int rtB = rtB0 + wj * 4;
    half8 bh[4][2];
#pragma unroll
    for (int jn = 0; jn < 4; ++jn) {
        size_t bb = (size_t)(rtB + jn) * 2 * 512 + loH;
        bh[jn][0] = *(const half8*)(EFh + bb);
        bh[jn][1] = *(const half8*)(EFh + bb + 512);
    }
    // hoisted predicate inputs: bj[jn] = ne_j - SEL_T (4 regs)
    float bj[4];
#pragma unroll
    for (int jn = 0; jn < 4; ++jn) bj[jn] = sNeJ[(wj << 6) + jn * 16 + m] - SEL_T;

    float zj[4] = {}, nj_[4] = {};
#pragma unroll
    for (int im = 0; im < 4; ++im) {
        size_t ab = (size_t)(rtA + im) * 2 * 512 + loH;
        half8 ah0 = *(const half8*)(EFh + ab);
        half8 ah1 = *(const half8*)(EFh + ab + 512);
        // one vector read: nei for rows quad*4..quad*4+3, pre-shifted
        int ibase = (wi << 6) + im * 16 + quad * 4;
        f32x4 ai4 = *(const f32x4*)(sNeI + ibase);
        ai4[0] -= SEL_T; ai4[1] -= SEL_T; ai4[2] -= SEL_T; ai4[3] -= SEL_T;
        f32x4 zi4 = {0.f, 0.f, 0.f, 0.f};
        f32x4 ni4 = {0.f, 0.f, 0.f, 0.f};
#pragma unroll
        for (int jn = 0; jn < 4; ++jn) {
            f32x4 acc = {0.f, 0.f, 0.f, 0.f};
            acc = MFMA16(ah0, bh[jn][0], acc);
            acc = MFMA16(ah1, bh[jn][1], acc);
            int jl = (wj << 6) + jn * 16 + m;
            int jg = j0 + jl;
            bool p[4];
            bool anyp = false;
#pragma unroll
            for (int r = 0; r < 4; ++r) {
                int ig = i0 + ibase + r;
                p[r] = (acc[r] > fminf(ai4[r], bj[jn])) && (!diag || ig < jg);
                anyp |= p[r];
            }
            if (__builtin_amdgcn_ballot_w64(anyp)) {   // wave-uniform skip
                float nej = sNeJ[jl], nnj = sNJ[jl];
                f32x4 g4 = gacc[im][jn];
#pragma unroll
                for (int r = 0; r < 4; ++r) {
                    if (p[r]) {
                        int il = ibase + r;
                        float nei = sNeI[il], nni = sNI[il];
                        float s = acc[r];
                        float wiw = __expf(s - nei);
                        float wjw = __expf(s - nej);
                        float wd = nni + nnj - 2.f * g4[r];
                        zi4[r] += wiw;  ni4[r] += wiw * wd;
                        zj[jn] += wjw;  nj_[jn] += wjw * wd;
                    }
                }
            }
        }
        // i-side: 2-stage reduce (groups of 4 m-lanes), write 4 partials/row
#pragma unroll
        for (int msk = 1; msk < 4; msk <<= 1) {
#pragma unroll
            for (int r = 0; r < 4; ++r) {
                zi4[r] += __shfl_xor(zi4[r], msk, 64);
                ni4[r] += __shfl_xor(ni4[r], msk, 64);
            }
        }
        if ((m & 3) == 0) {
            int k = m >> 2;
            int row0 = ibase;
            *(f32x4*)(scr + ((wj << 2) + k) * 128 + row0)        = zi4;
            *(f32x4*)(scr + 1024 + ((wj << 2) + k) * 128 + row0) = ni4;
        }
    }
    // j-side: 1-stage reduce (quad pairs), write 2 partials/col
#pragma unroll
    for (int jn = 0; jn < 4; ++jn) {
        zj[jn]  += __shfl_xor(zj[jn],  16, 64);
        nj_[jn] += __shfl_xor(nj_[jn], 16, 64);
    }
    if ((quad & 1) == 0) {
        int h = quad >> 1;
#pragma unroll
        for (int jn = 0; jn < 4; ++jn) {
            int jl = (wj << 6) + jn * 16 + m;
            scr[2048 + ((wi << 1) + h) * 128 + jl] = zj[jn];
            scr[2560 + ((wi << 1) + h) * 128 + jl] = nj_[jn];
        }
    }
    __syncthreads();
    // fold partial planes -> direct device atomics (zero-skip for empty rows)
    if (tid < 128) {
        float az = 0.f, an = 0.f;
#pragma unroll
        for (int p = 0; p < 8; ++p) {
            az += scr[p * 128 + tid];
            an += scr[1024 + p * 128 + tid];
        }
        if (az != 0.f || an != 0.f) {
            atomicAdd(Z + i0 + tid,   az);
            atomicAdd(num + i0 + tid, an);
        }
    } else {
        int cidx = tid - 128;
        float az = scr[2048 + cidx] + scr[2176 + cidx] + scr[2304 + cidx] + scr[2432 + cidx];
        float an = scr[2560 + cidx] + scr[2688 + cidx] + scr[2816 + cidx] + scr[2944 + cidx];
        if (az != 0.f || an != 0.f) {
            atomicAdd(Z + j0 + cidx,   az);
            atomicAdd(num + j0 + cidx, an);
        }
    }
}

// ------- K3: trivial 8192-row reduce + last-block final fold ------------
__global__ __launch_bounds__(256) void k_red(
    const float* __restrict__ Z, const float* __restrict__ num,
    double* __restrict__ part, unsigned* __restrict__ cnt,
    float* __restrict__ out) {
    int r = (blockIdx.x << 8) + threadIdx.x;   // 32 blocks x 256 threads
    __shared__ double sd[256];
    sd[threadIdx.x] = (double)num[r] / (double)Z[r];
    __syncthreads();
    for (int st = 128; st > 0; st >>= 1) {
        if (threadIdx.x < st) sd[threadIdx.x] += sd[threadIdx.x + st];
        __syncthreads();
    }
    if (threadIdx.x == 0) {
        part[blockIdx.x] = sd[0];
        __threadfence();
        unsigned old = atomicAdd(cnt, 1u);
        if (old == 31u) {                // last block folds
            __threadfence();
            double a = 0.0;
            for (int k = 0; k < 32; ++k) a += part[k];
            out[0] = (float)(a / 67108864.0);   // / B^2
        }
    }
}

// ---------------- host launcher -----------------------------------------
extern "C" void kernel_launch(void* const* d_in, const int* in_sizes, int n_in,
                              void* d_out, int out_size, void* d_ws, size_t ws_size,
                              hipStream_t stream) {
    const float* V = (const float*)d_in[0];   // [8192, 512] f32
    const float* E = (const float*)d_in[1];   // [8192, 64]  f32
    float* out = (float*)d_out;
    char* ws = (char*)d_ws;

    float*         n_   = (float*)(ws + 0);            // 32 KB
    float*         ne   = (float*)(ws + 32768);        // 32 KB
    float*         Z    = (float*)(ws + 65536);        // 32 KB (init 1 in k_prep)
    float*         num  = (float*)(ws + 98304);        // 32 KB (init 0 in k_prep)
    unsigned char* VF8  = (unsigned char*)(ws + 131072);// 4 MB fp8 V frags
    _Float16*      EFh  = (_Float16*)(ws + 4325376);   // 1 MB
    double*        part = (double*)(ws + 5373952);     // 256 B
    unsigned*      cnt  = (unsigned*)(ws + 5374208);   // 4 B

    k_prep<<<512, 256, 0, stream>>>(V, E, n_, ne, Z, num, VF8, EFh, cnt);
    k_mega<<<2080, 256, 0, stream>>>(VF8, EFh, ne, n_, Z, num);
    k_red <<<32, 256, 0, stream>>>(Z, num, part, cnt, out);
}